// Round 2
// baseline (8999.264 us; speedup 1.0000x reference)
//
#include <hip/hip_runtime.h>
#include <hip/hip_bf16.h>
#include <math.h>

#define BB 2
#define SS 2048
#define HH 4096
#define NH 32
#define NKV 8
#define HD 128
#define KVD (NKV*HD)    // 1024
#define WIN 512         // mask: j <= i && i-j <= 512
#define MROWS (BB*SS)   // 4096

#define DT_BF16 1
#define DT_F32  2

typedef __hip_bfloat16 bf16;

__device__ __forceinline__ float ldf(const bf16* p){ return __bfloat162float(*p); }
__device__ __forceinline__ float ldf(const float* p){ return *p; }
__device__ __forceinline__ void stf(bf16* p, float v){ *p = __float2bfloat16(v); }
__device__ __forceinline__ void stf(float* p, float v){ *p = v; }

// ---------- dtype detector: scan Wq's first 2048 bf16-interpretations ----------
// Real bf16 weights (std 1/64) have exponent ~121. If the buffer is fp32, the
// even-indexed halves are random mantissa bits -> exponent >=160 almost surely.
__global__ void detect_kernel(const void* __restrict__ w, int* __restrict__ flag)
{
  __shared__ int big;
  if (threadIdx.x == 0) big = 0;
  __syncthreads();
  const unsigned short* u = (const unsigned short*)w;
  for (int i = threadIdx.x; i < 2048; i += 256) {
    int ex = (u[i] >> 7) & 0xFF;
    if (ex >= 160) big = 1;
  }
  __syncthreads();
  if (threadIdx.x == 0) *flag = big ? DT_F32 : DT_BF16;
}

// ---------------- GEMM: C[M,N] = A[M,K] @ B[K,N]; row-major ----------------
// 64x64 tile, 256 threads, 4x4 micro-tile, fp32 accumulate. Gated on dtype flag.
template<typename TA, typename TB, typename TC>
__global__ __launch_bounds__(256)
void gemm64(const int* __restrict__ flag, int mydt,
            const TA* __restrict__ A, const TB* __restrict__ Bm,
            TC* __restrict__ C, int M, int N, int K)
{
  if (*flag != mydt) return;
  __shared__ float As[16][64];
  __shared__ float Bs[16][64];
  const int tx = threadIdx.x, ty = threadIdx.y;
  const int tid = ty*16 + tx;
  const int tM = blockIdx.y*64, tN = blockIdx.x*64;
  float c[4][4] = {{0.f}};

  for (int k0 = 0; k0 < K; k0 += 16) {
    { // A tile: 64 rows x 16 k
      int m  = tid >> 2;
      int kk = (tid & 3) * 4;
      const TA* ap = A + (size_t)(tM + m)*K + k0 + kk;
      #pragma unroll
      for (int j = 0; j < 4; j++) As[kk+j][m] = ldf(ap + j);
    }
    { // B tile: 16 k x 64 n (coalesced)
      int kk = tid >> 4;
      int n  = (tid & 15) * 4;
      const TB* bp = Bm + (size_t)(k0 + kk)*N + tN + n;
      #pragma unroll
      for (int j = 0; j < 4; j++) Bs[kk][n+j] = ldf(bp + j);
    }
    __syncthreads();
    #pragma unroll
    for (int kk = 0; kk < 16; kk++) {
      float a[4], b[4];
      #pragma unroll
      for (int i = 0; i < 4; i++) a[i] = As[kk][ty*4+i];
      #pragma unroll
      for (int j = 0; j < 4; j++) b[j] = Bs[kk][tx*4+j];
      #pragma unroll
      for (int i = 0; i < 4; i++)
        #pragma unroll
        for (int j = 0; j < 4; j++)
          c[i][j] = fmaf(a[i], b[j], c[i][j]);
    }
    __syncthreads();
  }

  #pragma unroll
  for (int i = 0; i < 4; i++)
    #pragma unroll
    for (int j = 0; j < 4; j++)
      stf(C + (size_t)(tM + ty*4 + i)*N + tN + tx*4 + j, c[i][j]);
}

// ---------------- RoPE (in place, bf16 [MROWS, nh*HD]) ----------------
__global__ void rope_kernel(bf16* __restrict__ X, int nh)
{
  int idx = blockIdx.x*blockDim.x + threadIdx.x;
  int total = MROWS * nh * 64;
  if (idx >= total) return;
  int f   = idx & 63;
  int h   = (idx >> 6) % nh;
  int row = (idx >> 6) / nh;
  int s   = row & (SS - 1);
  float ang = (float)s * powf(10000.0f, -(float)f * (1.0f/64.0f));
  float cv = cosf(ang), sv = sinf(ang);
  size_t base = (size_t)row*nh*HD + (size_t)h*HD;
  float x1 = ldf(X + base + f), x2 = ldf(X + base + 64 + f);
  stf(X + base + f,      x1*cv - x2*sv);
  stf(X + base + 64 + f, x2*cv + x1*sv);
}

// ---------------- Attention: one block per (b, h, i); 128 threads ----------------
__global__ __launch_bounds__(128)
void attn_kernel(const bf16* __restrict__ Q, const bf16* __restrict__ K,
                 const bf16* __restrict__ V, bf16* __restrict__ Aout)
{
  const int i = blockIdx.x;
  const int h = blockIdx.y;
  const int b = blockIdx.z;
  const int kh = h >> 2;            // GQA: 4 q-heads per kv head
  const int t = threadIdx.x;        // 0..127

  __shared__ float qs[HD];
  __shared__ float sc[WIN + 1];     // up to 513 scores
  __shared__ float red[128];

  const int jlo = (i > WIN) ? (i - WIN) : 0;
  const int nj  = i - jlo + 1;

  qs[t] = ldf(Q + (size_t)(b*SS + i)*HH + (size_t)h*HD + t);
  __syncthreads();

  const float scale = 0.08838834764831845f;   // 1/sqrt(128)

  float lmax = -1e30f;
  for (int jj = t; jj < nj; jj += 128) {
    const bf16* kr = K + (size_t)(b*SS + jlo + jj)*KVD + (size_t)kh*HD;
    float dot = 0.f;
    #pragma unroll 8
    for (int d = 0; d < HD; d++) dot = fmaf(qs[d], ldf(kr + d), dot);
    dot *= scale;
    sc[jj] = dot;
    lmax = fmaxf(lmax, dot);
  }
  red[t] = lmax; __syncthreads();
  for (int off = 64; off > 0; off >>= 1) {
    if (t < off) red[t] = fmaxf(red[t], red[t + off]);
    __syncthreads();
  }
  float m = red[0];
  __syncthreads();

  float lsum = 0.f;
  for (int jj = t; jj < nj; jj += 128) {
    float e = expf(sc[jj] - m);
    sc[jj] = e;
    lsum += e;
  }
  red[t] = lsum; __syncthreads();
  for (int off = 64; off > 0; off >>= 1) {
    if (t < off) red[t] += red[t + off];
    __syncthreads();
  }
  float linv = 1.0f / red[0];

  float acc = 0.f;
  for (int jj = 0; jj < nj; jj++) {
    acc = fmaf(sc[jj], ldf(V + (size_t)(b*SS + jlo + jj)*KVD + (size_t)kh*HD + t), acc);
  }
  stf(Aout + (size_t)(b*SS + i)*HH + (size_t)h*HD + t, acc * linv);
}

extern "C" void kernel_launch(void* const* d_in, const int* in_sizes, int n_in,
                              void* d_out, int out_size, void* d_ws, size_t ws_size,
                              hipStream_t stream)
{
  char* ws = (char*)d_ws;
  int*  flag = (int*)ws;
  bf16* Q = (bf16*)(ws + 256);                                   // 32 MB
  bf16* K = (bf16*)(ws + 256 + ((size_t)32 << 20));              // 8 MB
  bf16* V = (bf16*)(ws + 256 + ((size_t)40 << 20));              // 8 MB
  bf16* A = (bf16*)(ws + 256 + ((size_t)48 << 20));              // 32 MB

  detect_kernel<<<1, 256, 0, stream>>>(d_in[1], flag);

  dim3 blk(16, 16);

  // ---- bf16-input pipeline (gated) ----
  {
    const bf16* X  = (const bf16*)d_in[0];
    const bf16* Wq = (const bf16*)d_in[1];
    const bf16* Wk = (const bf16*)d_in[2];
    const bf16* Wv = (const bf16*)d_in[3];
    const bf16* Wo = (const bf16*)d_in[4];
    gemm64<<<dim3(HH/64,  MROWS/64), blk, 0, stream>>>(flag, DT_BF16, X, Wq, Q, MROWS, HH,  HH);
    gemm64<<<dim3(KVD/64, MROWS/64), blk, 0, stream>>>(flag, DT_BF16, X, Wk, K, MROWS, KVD, HH);
    gemm64<<<dim3(KVD/64, MROWS/64), blk, 0, stream>>>(flag, DT_BF16, X, Wv, V, MROWS, KVD, HH);
  }
  // ---- fp32-input pipeline (gated) ----
  {
    const float* X  = (const float*)d_in[0];
    const float* Wq = (const float*)d_in[1];
    const float* Wk = (const float*)d_in[2];
    const float* Wv = (const float*)d_in[3];
    gemm64<<<dim3(HH/64,  MROWS/64), blk, 0, stream>>>(flag, DT_F32, X, Wq, Q, MROWS, HH,  HH);
    gemm64<<<dim3(KVD/64, MROWS/64), blk, 0, stream>>>(flag, DT_F32, X, Wk, K, MROWS, KVD, HH);
    gemm64<<<dim3(KVD/64, MROWS/64), blk, 0, stream>>>(flag, DT_F32, X, Wv, V, MROWS, KVD, HH);
  }

  // ---- dtype-independent middle ----
  rope_kernel<<<(MROWS*NH *64 + 255)/256, 256, 0, stream>>>(Q, NH);
  rope_kernel<<<(MROWS*NKV*64 + 255)/256, 256, 0, stream>>>(K, NKV);
  attn_kernel<<<dim3(SS, NH, BB), 128, 0, stream>>>(Q, K, V, A);

  // ---- output projection, dtype-gated ----
  gemm64<<<dim3(HH/64, MROWS/64), blk, 0, stream>>>(flag, DT_BF16, A, (const bf16*)d_in[4],
                                                    (bf16*)d_out, MROWS, HH, HH);
  gemm64<<<dim3(HH/64, MROWS/64), blk, 0, stream>>>(flag, DT_F32,  A, (const float*)d_in[4],
                                                    (float*)d_out, MROWS, HH, HH);
}